// Round 6
// baseline (1031.744 us; speedup 1.0000x reference)
//
#include <hip/hip_runtime.h>
#include <hip/hip_bf16.h>

// SimVQ forward for MI355X (gfx950).
// z:[32768,512] f32, embedding:[8192,512], proj weights 512x512.
// Outputs concatenated: quantized[16777216] f32, vq_loss[1] f32, idx[32768] (as f32).
//
// idx = argmax_n z_proj . c_n  (z-normalization is a positive per-row scale -> argmin-invariant)
//     = argmax_n  z . (Wz^T c_n) + bz . c_n
// R3: loss via per-block partials (atomicAdd serialization fix).
// R4 FAILED: 64x128 wave tile spilled accumulators (WRITE_SIZE 17.8 GB) -> 3430 us.
//     64x64 wave tile @ ~76 VGPR + 64 AGPR is the register sweet spot.
// R5: small GEMMs (qc, e) moved to split-bf16 MFMA; non-scores time 262->150 us.
// R6: two-pass argmax. Pass 1: SINGLE-product bf16 MFMA (1/3 the FLOPs of the
//     3-term scheme), stores all scores as bf16 (512 MB ws) + approx row max.
//     Pass 2: per row, exact fp32 rescore of every candidate within a HARD-BOUND
//     margin of the approx max (err <= 2*2^-8*|z|*|e|max + 2^-9*|s|); candidate
//     set provably contains the true argmax. Pass 2 fuses gather+loss.
//     Falls back to the proven R5 3-term path if ws_size < 638 MB.

#define NQ    32768
#define NEMB  8192
#define DD    512

typedef __attribute__((ext_vector_type(8))) short bf16x8;
typedef __attribute__((ext_vector_type(4))) float f32x4;

__device__ __forceinline__ unsigned short f2bf_rne(float f) {
    unsigned u = __float_as_uint(f);
    unsigned r = u + 0x7FFFu + ((u >> 16) & 1u);
    return (unsigned short)(r >> 16);
}
__device__ __forceinline__ float bf2f(unsigned short b) {
    return __uint_as_float(((unsigned)b) << 16);
}

__device__ __forceinline__ void gload16(const void* g, void* l) {
    __builtin_amdgcn_global_load_lds(
        (const __attribute__((address_space(1))) unsigned int*)g,
        (__attribute__((address_space(3))) unsigned int*)l, 16, 0, 0);
}

// ---------------- generic fp32 -> bf16 hi/lo split ---------------------------
__global__ __launch_bounds__(256) void k_split(const float* __restrict__ src,
                                               unsigned short* __restrict__ hi,
                                               unsigned short* __restrict__ lo,
                                               int n4) {
    const float4* s4 = (const float4*)src;
    ushort4* h4 = (ushort4*)hi;
    ushort4* l4 = (ushort4*)lo;
    for (int i = blockIdx.x * blockDim.x + threadIdx.x; i < n4; i += gridDim.x * blockDim.x) {
        float4 v = s4[i];
        ushort4 h, l;
        h.x = f2bf_rne(v.x); l.x = f2bf_rne(v.x - bf2f(h.x));
        h.y = f2bf_rne(v.y); l.y = f2bf_rne(v.y - bf2f(h.y));
        h.z = f2bf_rne(v.z); l.z = f2bf_rne(v.z - bf2f(h.z));
        h.w = f2bf_rne(v.w); l.w = f2bf_rne(v.w - bf2f(h.w));
        h4[i] = h;
        l4[i] = l;
    }
}

// hi-only split (fast path: pass 1 needs only z_hi)
__global__ __launch_bounds__(256) void k_split_hi(const float* __restrict__ src,
                                                  unsigned short* __restrict__ hi,
                                                  int n4) {
    const float4* s4 = (const float4*)src;
    ushort4* h4 = (ushort4*)hi;
    for (int i = blockIdx.x * blockDim.x + threadIdx.x; i < n4; i += gridDim.x * blockDim.x) {
        float4 v = s4[i];
        ushort4 h;
        h.x = f2bf_rne(v.x);
        h.y = f2bf_rne(v.y);
        h.z = f2bf_rne(v.z);
        h.w = f2bf_rne(v.w);
        h4[i] = h;
    }
}

// ---------------- transpose + split: T[k][d] = W[d][k] -----------------------
__global__ __launch_bounds__(256) void k_wtsplit(const float* __restrict__ W,
                                                 unsigned short* __restrict__ thi,
                                                 unsigned short* __restrict__ tlo) {
    __shared__ float t[32][33];
    const int bx = blockIdx.x * 32;  // output row block (k)
    const int by = blockIdx.y * 32;  // output col block (d)
    const int c = threadIdx.x & 31, r0 = threadIdx.x >> 5;
    for (int i = 0; i < 4; ++i) {
        int r = r0 + i * 8;
        t[r][c] = W[(size_t)(by + r) * DD + bx + c];
    }
    __syncthreads();
    for (int i = 0; i < 4; ++i) {
        int r = r0 + i * 8;
        float v = t[c][r];  // = W[by+c][bx+r]
        unsigned short h = f2bf_rne(v);
        thi[(size_t)(bx + r) * DD + by + c] = h;
        tlo[(size_t)(bx + r) * DD + by + c] = f2bf_rne(v - bf2f(h));
    }
}

// ---------------- MFMA GEMM core macro-structure -----------------------------
// Block tile 128(m) x 128(n), BK=32, 4 waves 2x2, wave tile 64x64.
// XOR bank swizzle: k-group kg of row m stored at kg^((m>>1)&3) (verified R2:
// 0 bank conflicts; staging stays fully coalesced under global_load_lds).

// Kernel: qc = emb @ Wp^T + bp  (writes fp32 qc AND its bf16 hi/lo split)
__global__ __launch_bounds__(256, 3) void k_qc_mfma(const unsigned short* __restrict__ Ah,
                                                    const unsigned short* __restrict__ Al,
                                                    const unsigned short* __restrict__ Bh,
                                                    const unsigned short* __restrict__ Bl,
                                                    const float* __restrict__ bias,
                                                    float* __restrict__ qc,
                                                    unsigned short* __restrict__ qhi,
                                                    unsigned short* __restrict__ qlo) {
    __shared__ unsigned short sAh[128 * 32];
    __shared__ unsigned short sAl[128 * 32];
    __shared__ unsigned short sBh[128 * 32];
    __shared__ unsigned short sBl[128 * 32];

    const int t    = threadIdx.x;
    const int lane = t & 63;
    const int wave = t >> 6;
    const int wm   = wave >> 1;
    const int wn   = wave & 1;
    const int m0   = blockIdx.y * 128;
    const int n0   = blockIdx.x * 128;

    f32x4 acc[4][4];
    for (int i = 0; i < 4; ++i)
        for (int j = 0; j < 4; ++j) acc[i][j] = (f32x4){0.f, 0.f, 0.f, 0.f};

    const int koff = (((lane >> 4) ^ ((lane >> 1) & 3)) << 3);

    for (int kb = 0; kb < DD; kb += 32) {
        for (int r = 0; r < 2; ++r) {
            const int cbase = r * 256 + wave * 64;
            const int c = cbase + lane;
            const int m = c >> 2;
            const int kg = (c & 3) ^ ((m >> 1) & 3);
            const size_t ga = (size_t)(m0 + m) * DD + kb + kg * 8;
            const size_t gb = (size_t)(n0 + m) * DD + kb + kg * 8;
            gload16(Ah + ga, &sAh[cbase * 8]);
            gload16(Al + ga, &sAl[cbase * 8]);
            gload16(Bh + gb, &sBh[cbase * 8]);
            gload16(Bl + gb, &sBl[cbase * 8]);
        }
        __syncthreads();

        bf16x8 afh[4], afl[4], bfh[4], bfl[4];
        const int ar = wm * 64 + (lane & 15);
        const int br = wn * 64 + (lane & 15);
        for (int i = 0; i < 4; ++i) {
            afh[i] = *(const bf16x8*)&sAh[(ar + i * 16) * 32 + koff];
            afl[i] = *(const bf16x8*)&sAl[(ar + i * 16) * 32 + koff];
            bfh[i] = *(const bf16x8*)&sBh[(br + i * 16) * 32 + koff];
            bfl[i] = *(const bf16x8*)&sBl[(br + i * 16) * 32 + koff];
        }
        for (int i = 0; i < 4; ++i)
            for (int j = 0; j < 4; ++j) {
                acc[i][j] = __builtin_amdgcn_mfma_f32_16x16x32_bf16(afh[i], bfh[j], acc[i][j], 0, 0, 0);
                acc[i][j] = __builtin_amdgcn_mfma_f32_16x16x32_bf16(afh[i], bfl[j], acc[i][j], 0, 0, 0);
                acc[i][j] = __builtin_amdgcn_mfma_f32_16x16x32_bf16(afl[i], bfh[j], acc[i][j], 0, 0, 0);
            }
        __syncthreads();
    }

    // epilogue: C/D layout col=lane&15, row=(lane>>4)*4+reg
    const int colb = lane & 15;
    const int g    = lane >> 4;
    float bcol[4];
    for (int tn = 0; tn < 4; ++tn) bcol[tn] = bias[n0 + wn * 64 + tn * 16 + colb];
    for (int tm = 0; tm < 4; ++tm) {
        for (int reg = 0; reg < 4; ++reg) {
            int row = m0 + wm * 64 + tm * 16 + g * 4 + reg;
            for (int tn = 0; tn < 4; ++tn) {
                int col = n0 + wn * 64 + tn * 16 + colb;
                float v = acc[tm][tn][reg] + bcol[tn];
                size_t o = (size_t)row * DD + col;
                qc[o] = v;
                unsigned short h = f2bf_rne(v);
                qhi[o] = h;
                qlo[o] = f2bf_rne(v - bf2f(h));
            }
        }
    }
}

// Kernel: e = rnorm .* (qc @ Wz)  via transposed-split Wz; writes bf16 hi/lo.
__global__ __launch_bounds__(256, 3) void k_e_mfma(const unsigned short* __restrict__ Ah,
                                                   const unsigned short* __restrict__ Al,
                                                   const unsigned short* __restrict__ Bh,
                                                   const unsigned short* __restrict__ Bl,
                                                   const float* __restrict__ rnorm,
                                                   unsigned short* __restrict__ ehi,
                                                   unsigned short* __restrict__ elo) {
    __shared__ unsigned short sAh[128 * 32];
    __shared__ unsigned short sAl[128 * 32];
    __shared__ unsigned short sBh[128 * 32];
    __shared__ unsigned short sBl[128 * 32];

    const int t    = threadIdx.x;
    const int lane = t & 63;
    const int wave = t >> 6;
    const int wm   = wave >> 1;
    const int wn   = wave & 1;
    const int m0   = blockIdx.y * 128;
    const int n0   = blockIdx.x * 128;

    f32x4 acc[4][4];
    for (int i = 0; i < 4; ++i)
        for (int j = 0; j < 4; ++j) acc[i][j] = (f32x4){0.f, 0.f, 0.f, 0.f};

    const int koff = (((lane >> 4) ^ ((lane >> 1) & 3)) << 3);

    for (int kb = 0; kb < DD; kb += 32) {
        for (int r = 0; r < 2; ++r) {
            const int cbase = r * 256 + wave * 64;
            const int c = cbase + lane;
            const int m = c >> 2;
            const int kg = (c & 3) ^ ((m >> 1) & 3);
            const size_t ga = (size_t)(m0 + m) * DD + kb + kg * 8;
            const size_t gb = (size_t)(n0 + m) * DD + kb + kg * 8;
            gload16(Ah + ga, &sAh[cbase * 8]);
            gload16(Al + ga, &sAl[cbase * 8]);
            gload16(Bh + gb, &sBh[cbase * 8]);
            gload16(Bl + gb, &sBl[cbase * 8]);
        }
        __syncthreads();

        bf16x8 afh[4], afl[4], bfh[4], bfl[4];
        const int ar = wm * 64 + (lane & 15);
        const int br = wn * 64 + (lane & 15);
        for (int i = 0; i < 4; ++i) {
            afh[i] = *(const bf16x8*)&sAh[(ar + i * 16) * 32 + koff];
            afl[i] = *(const bf16x8*)&sAl[(ar + i * 16) * 32 + koff];
            bfh[i] = *(const bf16x8*)&sBh[(br + i * 16) * 32 + koff];
            bfl[i] = *(const bf16x8*)&sBl[(br + i * 16) * 32 + koff];
        }
        for (int i = 0; i < 4; ++i)
            for (int j = 0; j < 4; ++j) {
                acc[i][j] = __builtin_amdgcn_mfma_f32_16x16x32_bf16(afh[i], bfh[j], acc[i][j], 0, 0, 0);
                acc[i][j] = __builtin_amdgcn_mfma_f32_16x16x32_bf16(afh[i], bfl[j], acc[i][j], 0, 0, 0);
                acc[i][j] = __builtin_amdgcn_mfma_f32_16x16x32_bf16(afl[i], bfh[j], acc[i][j], 0, 0, 0);
            }
        __syncthreads();
    }

    const int colb = lane & 15;
    const int g    = lane >> 4;
    for (int tm = 0; tm < 4; ++tm) {
        const int rbase = m0 + wm * 64 + tm * 16 + g * 4;
        float4 rn4 = *(const float4*)&rnorm[rbase];
        const float rnv[4] = {rn4.x, rn4.y, rn4.z, rn4.w};
        for (int reg = 0; reg < 4; ++reg) {
            int row = rbase + reg;
            for (int tn = 0; tn < 4; ++tn) {
                int col = n0 + wn * 64 + tn * 16 + colb;
                float v = acc[tm][tn][reg] * rnv[reg];
                size_t o = (size_t)row * DD + col;
                unsigned short h = f2bf_rne(v);
                ehi[o] = h;
                elo[o] = f2bf_rne(v - bf2f(h));
            }
        }
    }
}

// ---------------- per-row 1/norm and t_n numerator ---------------------------
__global__ __launch_bounds__(256) void k_norm(const float* __restrict__ qc,
                                              const float* __restrict__ bz,
                                              float* __restrict__ rnorm,
                                              float* __restrict__ tvec) {
    const int n = blockIdx.x;
    const int t = threadIdx.x;
    float ss = 0.f, tb = 0.f;
    for (int d = t; d < DD; d += 256) {
        float v = qc[(size_t)n * DD + d];
        ss += v * v;
        tb += bz[d] * v;
    }
    for (int off = 32; off; off >>= 1) {
        ss += __shfl_down(ss, off);
        tb += __shfl_down(tb, off);
    }
    __shared__ float s1[4], s2[4];
    int wave = t >> 6, lane = t & 63;
    if (lane == 0) { s1[wave] = ss; s2[wave] = tb; }
    __syncthreads();
    if (t == 0) {
        ss = s1[0] + s1[1] + s1[2] + s1[3];
        tb = s2[0] + s2[1] + s2[2] + s2[3];
        float norm = sqrtf(ss);
        float rn = 1.f / fmaxf(norm, 1e-12f);
        rnorm[n] = rn;
        tvec[n] = tb * rn;  // bz . c_n (normalized)
    }
}

// ---------------- FAST pass 1: single-product scores + bf16 store + row max --
__global__ __launch_bounds__(256, 3) void k_scores1(const unsigned short* __restrict__ Ah,
                                                    const unsigned short* __restrict__ Bh,
                                                    const float* __restrict__ tvec,
                                                    unsigned long long* __restrict__ table,
                                                    unsigned short* __restrict__ scores) {
    __shared__ unsigned short sAh[128 * 32];
    __shared__ unsigned short sBh[128 * 32];

    const int t    = threadIdx.x;
    const int lane = t & 63;
    const int wave = t >> 6;
    const int wm   = wave >> 1;
    const int wn   = wave & 1;
    const int m0   = blockIdx.y * 128;
    const int n0   = blockIdx.x * 128;

    f32x4 acc[4][4];
    for (int i = 0; i < 4; ++i)
        for (int j = 0; j < 4; ++j) acc[i][j] = (f32x4){0.f, 0.f, 0.f, 0.f};

    const int koff = (((lane >> 4) ^ ((lane >> 1) & 3)) << 3);

    for (int kb = 0; kb < DD; kb += 32) {
        for (int r = 0; r < 2; ++r) {
            const int cbase = r * 256 + wave * 64;
            const int c = cbase + lane;
            const int m = c >> 2;
            const int kg = (c & 3) ^ ((m >> 1) & 3);
            const size_t ga = (size_t)(m0 + m) * DD + kb + kg * 8;
            const size_t gb = (size_t)(n0 + m) * DD + kb + kg * 8;
            gload16(Ah + ga, &sAh[cbase * 8]);
            gload16(Bh + gb, &sBh[cbase * 8]);
        }
        __syncthreads();

        bf16x8 afh[4], bfh[4];
        const int ar = wm * 64 + (lane & 15);
        const int br = wn * 64 + (lane & 15);
        for (int i = 0; i < 4; ++i) {
            afh[i] = *(const bf16x8*)&sAh[(ar + i * 16) * 32 + koff];
            bfh[i] = *(const bf16x8*)&sBh[(br + i * 16) * 32 + koff];
        }
        for (int i = 0; i < 4; ++i)
            for (int j = 0; j < 4; ++j)
                acc[i][j] = __builtin_amdgcn_mfma_f32_16x16x32_bf16(afh[i], bfh[j], acc[i][j], 0, 0, 0);
        __syncthreads();
    }

    // epilogue: add t_n, store bf16 scores, row-wise approx argmax -> atomicMax
    const int col = lane & 15;
    const int g   = lane >> 4;
    float tc[4];
    for (int tn = 0; tn < 4; ++tn) tc[tn] = tvec[n0 + wn * 64 + tn * 16 + col];

    for (int tm = 0; tm < 4; ++tm) {
        for (int reg = 0; reg < 4; ++reg) {
            const int q = m0 + wm * 64 + tm * 16 + g * 4 + reg;
            float best = -3.4e38f;
            int   bn   = 0x7FFFFFFF;
            for (int tn = 0; tn < 4; ++tn) {
                float v = acc[tm][tn][reg] + tc[tn];
                int n = n0 + wn * 64 + tn * 16 + col;
                scores[(size_t)q * NEMB + n] = f2bf_rne(v);
                if (v > best || (v == best && n < bn)) { best = v; bn = n; }
            }
            for (int off = 1; off < 16; off <<= 1) {
                float ov = __shfl_xor(best, off);
                int   on = __shfl_xor(bn, off);
                if (ov > best || (ov == best && on < bn)) { best = ov; bn = on; }
            }
            if (col == 0) {
                unsigned u = __float_as_uint(best);
                unsigned key = (u & 0x80000000u) ? ~u : (u | 0x80000000u);
                unsigned long long packed =
                    ((unsigned long long)key << 32) |
                    (unsigned long long)(0xFFFFFFFFu - (unsigned)bn);
                atomicMax(&table[q], packed);
            }
        }
    }
}

// ---------------- FAST pass 2: candidate rescore + gather + loss -------------
// Hard error bound: |s_mfma - s_true| <= 2^-8*1.01*|z|*|e|max (|e|<=1.5) per
// entry; bf16 store adds 2^-9*|s|. Margin 0.02*|z| + 0.01*(|max|+1) covers
// 2x MFMA err + store err with >2x slack -> candidate set contains true argmax.
__global__ __launch_bounds__(256) void k_select(const unsigned long long* __restrict__ table,
                                                const unsigned short* __restrict__ scores,
                                                const float* __restrict__ z,
                                                const float* __restrict__ tvec,
                                                const unsigned short* __restrict__ ehi,
                                                const unsigned short* __restrict__ elo,
                                                const float* __restrict__ qc,
                                                float* __restrict__ outq,
                                                float* __restrict__ partials,
                                                float* __restrict__ outidx) {
    const int q = blockIdx.x;
    const int t = threadIdx.x;
    const int lane = t & 63;
    const int wave = t >> 6;
    __shared__ float zrow[DD];
    __shared__ float sred[4];
    __shared__ unsigned long long sred64[4];
    __shared__ int sidx;

    // 1) stage z row in LDS, compute |z|^2
    float zz = 0.f;
    for (int d = t; d < DD; d += 256) {
        float v = z[(size_t)q * DD + d];
        zrow[d] = v;
        zz += v * v;
    }
    for (int off = 32; off; off >>= 1) zz += __shfl_down(zz, off);
    if (lane == 0) sred[wave] = zz;
    __syncthreads();
    const float znorm = sqrtf(sred[0] + sred[1] + sred[2] + sred[3]);

    // 2) unpack approx max, scan + exact rescore of candidates
    unsigned long long p = table[q];
    unsigned key = (unsigned)(p >> 32);
    float maxv = (key & 0x80000000u) ? __uint_as_float(key & 0x7FFFFFFFu)
                                     : __uint_as_float(~key);
    const float thr = maxv - (0.02f * znorm + 0.01f * (fabsf(maxv) + 1.0f));

    float bbest = -3.4e38f;
    int   bbn   = 0x7FFFFFFF;
    const unsigned short* srow = scores + (size_t)q * NEMB + t * 32;
    for (int c = 0; c < 4; ++c) {
        ushort4 u0 = *(const ushort4*)(srow + c * 8);
        ushort4 u1 = *(const ushort4*)(srow + c * 8 + 4);
        const unsigned short uu[8] = {u0.x, u0.y, u0.z, u0.w, u1.x, u1.y, u1.z, u1.w};
        for (int e = 0; e < 8; ++e) {
            if (bf2f(uu[e]) >= thr) {
                const int n = t * 32 + c * 8 + e;
                float s = tvec[n];
                const ushort4* eh = (const ushort4*)(ehi + (size_t)n * DD);
                const ushort4* el = (const ushort4*)(elo + (size_t)n * DD);
                for (int d4 = 0; d4 < DD / 4; ++d4) {
                    ushort4 h = eh[d4], l = el[d4];
                    s += zrow[d4 * 4 + 0] * (bf2f(h.x) + bf2f(l.x));
                    s += zrow[d4 * 4 + 1] * (bf2f(h.y) + bf2f(l.y));
                    s += zrow[d4 * 4 + 2] * (bf2f(h.z) + bf2f(l.z));
                    s += zrow[d4 * 4 + 3] * (bf2f(h.w) + bf2f(l.w));
                }
                if (s > bbest || (s == bbest && n < bbn)) { bbest = s; bbn = n; }
            }
        }
    }
    unsigned bu = __float_as_uint(bbest);
    unsigned bk = (bu & 0x80000000u) ? ~bu : (bu | 0x80000000u);
    unsigned long long pk = ((unsigned long long)bk << 32) |
                            (unsigned long long)(0xFFFFFFFFu - (unsigned)bbn);
    for (int off = 32; off; off >>= 1) {
        unsigned long long o = __shfl_down(pk, off);
        if (o > pk) pk = o;
    }
    if (lane == 0) sred64[wave] = pk;
    __syncthreads();
    if (t == 0) {
        unsigned long long m = sred64[0];
        for (int w = 1; w < 4; ++w) if (sred64[w] > m) m = sred64[w];
        int idx = (int)(0xFFFFFFFFu - (unsigned)(m & 0xFFFFFFFFull));
        sidx = idx;
        outidx[q] = (float)idx;
    }
    __syncthreads();
    const int idx = sidx;

    // 3) gather qc[idx] row -> out, per-row squared error
    float ss = 0.f;
    if (t < 128) {
        float4 a = *(const float4*)(qc + (size_t)idx * DD + t * 4);
        *(float4*)(outq + (size_t)q * DD + t * 4) = a;
        float d0 = a.x - zrow[t * 4 + 0];
        float d1 = a.y - zrow[t * 4 + 1];
        float d2 = a.z - zrow[t * 4 + 2];
        float d3 = a.w - zrow[t * 4 + 3];
        ss = d0 * d0 + d1 * d1 + d2 * d2 + d3 * d3;
    }
    for (int off = 32; off; off >>= 1) ss += __shfl_down(ss, off);
    __syncthreads();
    if (lane == 0) sred[wave] = ss;
    __syncthreads();
    if (t == 0) partials[q] = sred[0] + sred[1] + sred[2] + sred[3];
}

// ---------------- FALLBACK: 3-term scores + fused argmax (R5, 857 us) --------
__global__ __launch_bounds__(256, 3) void k_scores(const unsigned short* __restrict__ Ah,
                                                   const unsigned short* __restrict__ Al,
                                                   const unsigned short* __restrict__ Bh,
                                                   const unsigned short* __restrict__ Bl,
                                                   const float* __restrict__ tvec,
                                                   unsigned long long* __restrict__ table) {
    __shared__ unsigned short sAh[128 * 32];
    __shared__ unsigned short sAl[128 * 32];
    __shared__ unsigned short sBh[128 * 32];
    __shared__ unsigned short sBl[128 * 32];

    const int t    = threadIdx.x;
    const int lane = t & 63;
    const int wave = t >> 6;
    const int wm   = wave >> 1;
    const int wn   = wave & 1;
    const int m0   = blockIdx.y * 128;
    const int n0   = blockIdx.x * 128;

    f32x4 acc[4][4];
    for (int i = 0; i < 4; ++i)
        for (int j = 0; j < 4; ++j) acc[i][j] = (f32x4){0.f, 0.f, 0.f, 0.f};

    const int koff = (((lane >> 4) ^ ((lane >> 1) & 3)) << 3);

    for (int kb = 0; kb < DD; kb += 32) {
        for (int r = 0; r < 2; ++r) {
            const int cbase = r * 256 + wave * 64;
            const int c = cbase + lane;
            const int m = c >> 2;
            const int kg = (c & 3) ^ ((m >> 1) & 3);
            const size_t ga = (size_t)(m0 + m) * DD + kb + kg * 8;
            const size_t gb = (size_t)(n0 + m) * DD + kb + kg * 8;
            gload16(Ah + ga, &sAh[cbase * 8]);
            gload16(Al + ga, &sAl[cbase * 8]);
            gload16(Bh + gb, &sBh[cbase * 8]);
            gload16(Bl + gb, &sBl[cbase * 8]);
        }
        __syncthreads();

        bf16x8 afh[4], afl[4], bfh[4], bfl[4];
        const int ar = wm * 64 + (lane & 15);
        const int br = wn * 64 + (lane & 15);
        for (int i = 0; i < 4; ++i) {
            afh[i] = *(const bf16x8*)&sAh[(ar + i * 16) * 32 + koff];
            afl[i] = *(const bf16x8*)&sAl[(ar + i * 16) * 32 + koff];
            bfh[i] = *(const bf16x8*)&sBh[(br + i * 16) * 32 + koff];
            bfl[i] = *(const bf16x8*)&sBl[(br + i * 16) * 32 + koff];
        }
        for (int i = 0; i < 4; ++i)
            for (int j = 0; j < 4; ++j) {
                acc[i][j] = __builtin_amdgcn_mfma_f32_16x16x32_bf16(afh[i], bfh[j], acc[i][j], 0, 0, 0);
                acc[i][j] = __builtin_amdgcn_mfma_f32_16x16x32_bf16(afh[i], bfl[j], acc[i][j], 0, 0, 0);
                acc[i][j] = __builtin_amdgcn_mfma_f32_16x16x32_bf16(afl[i], bfh[j], acc[i][j], 0, 0, 0);
            }
        __syncthreads();
    }

    const int col = lane & 15;
    const int g   = lane >> 4;
    float tc[4];
    for (int tn = 0; tn < 4; ++tn) tc[tn] = tvec[n0 + wn * 64 + tn * 16 + col];

    for (int tm = 0; tm < 4; ++tm) {
        for (int reg = 0; reg < 4; ++reg) {
            float best = -3.4e38f;
            int   bn   = 0x7FFFFFFF;
            for (int tn = 0; tn < 4; ++tn) {
                float v = acc[tm][tn][reg] + tc[tn];
                int n = n0 + wn * 64 + tn * 16 + col;
                if (v > best || (v == best && n < bn)) { best = v; bn = n; }
            }
            for (int off = 1; off < 16; off <<= 1) {
                float ov = __shfl_xor(best, off);
                int   on = __shfl_xor(bn, off);
                if (ov > best || (ov == best && on < bn)) { best = ov; bn = on; }
            }
            if (col == 0) {
                unsigned u = __float_as_uint(best);
                unsigned key = (u & 0x80000000u) ? ~u : (u | 0x80000000u);
                unsigned long long packed =
                    ((unsigned long long)key << 32) |
                    (unsigned long long)(0xFFFFFFFFu - (unsigned)bn);
                int q = m0 + wm * 64 + tm * 16 + g * 4 + reg;
                atomicMax(&table[q], packed);
            }
        }
    }
}

// ---------------- FALLBACK gather ---------------------------------------------
__global__ __launch_bounds__(128) void k_gather(const unsigned long long* __restrict__ table,
                                                const float* __restrict__ qc,
                                                const float* __restrict__ z,
                                                float* __restrict__ outq,
                                                float* __restrict__ partials,
                                                float* __restrict__ outidx) {
    const int q = blockIdx.x;
    const int t = threadIdx.x;
    unsigned long long p = table[q];
    const int idx = (int)(0xFFFFFFFFu - (unsigned)(p & 0xFFFFFFFFull));
    const float4* src = (const float4*)(qc + (size_t)idx * DD);
    const float4* zs  = (const float4*)(z + (size_t)q * DD);
    float4* dst = (float4*)(outq + (size_t)q * DD);
    float4 a = src[t], b = zs[t];
    dst[t] = a;
    float dx = a.x - b.x, dy = a.y - b.y, dz = a.z - b.z, dw = a.w - b.w;
    float ss = dx * dx + dy * dy + dz * dz + dw * dw;
    for (int off = 32; off; off >>= 1) ss += __shfl_down(ss, off);
    __shared__ float sbuf[2];
    if ((t & 63) == 0) sbuf[t >> 6] = ss;
    __syncthreads();
    if (t == 0) {
        partials[q] = sbuf[0] + sbuf[1];
        outidx[q] = (float)idx;
    }
}

// ---------------- final loss reduction ---------------------------------------
__global__ __launch_bounds__(1024) void k_loss(const float* __restrict__ partials,
                                               float* __restrict__ loss) {
    const int t = threadIdx.x;
    float s = 0.f;
    for (int i = t; i < NQ; i += 1024) s += partials[i];
    for (int off = 32; off; off >>= 1) s += __shfl_down(s, off);
    __shared__ float sbuf[16];
    if ((t & 63) == 0) sbuf[t >> 6] = s;
    __syncthreads();
    if (t == 0) {
        float tot = 0.f;
        for (int w = 0; w < 16; ++w) tot += sbuf[w];
        // vq_loss = (1 + beta) * mean((quantized - z)^2), beta = 0.25
        *loss = tot * (1.25f / 16777216.0f);
    }
}

extern "C" void kernel_launch(void* const* d_in, const int* in_sizes, int n_in,
                              void* d_out, int out_size, void* d_ws, size_t ws_size,
                              hipStream_t stream) {
    (void)in_sizes; (void)n_in; (void)out_size;
    const float* z   = (const float*)d_in[0];   // [32768,512]
    const float* emb = (const float*)d_in[1];   // [8192,512]
    const float* Wp  = (const float*)d_in[2];   // emb_proj_w [512,512]
    const float* bp  = (const float*)d_in[3];   // emb_proj_b [512]
    const float* Wz  = (const float*)d_in[4];   // z_proj_w [512,512]
    const float* bz  = (const float*)d_in[5];   // z_proj_b [512]
    // d_in[6] = l2_scale: positive scalar, argmin-invariant -> unused

    float* out = (float*)d_out;
    char* ws = (char*)d_ws;
    // ws layout (bytes):
    float* qc            = (float*)(ws + 0);           // 16,777,216
    float* rnorm         = (float*)(ws + 16777216);    //     32,768
    float* tvec          = (float*)(ws + 16809984);    //     32,768
    unsigned short* ehi  = (unsigned short*)(ws + 16842752);   // 8,388,608
    unsigned short* elo  = (unsigned short*)(ws + 25231360);   // 8,388,608
    unsigned short* zhi  = (unsigned short*)(ws + 33619968);   // 33,554,432
    unsigned short* zlo  = (unsigned short*)(ws + 67174400);   // 33,554,432
    unsigned long long* table = (unsigned long long*)(ws + 100728832); // 262,144
    unsigned short* scores    = (unsigned short*)(ws + 100990976);     // 536,870,912 (fast path)

    // Phase-overlapped aliases (dead before their region is overwritten):
    unsigned short* embhi = (unsigned short*)(ws + 33619968);
    unsigned short* emblo = (unsigned short*)(ws + 33619968 + 8388608);
    unsigned short* qchi  = (unsigned short*)(ws + 33619968 + 16777216);
    unsigned short* qclo  = (unsigned short*)(ws + 33619968 + 25165824);
    unsigned short* wphi  = (unsigned short*)(ws + 67174400);
    unsigned short* wplo  = (unsigned short*)(ws + 67174400 + 524288);
    unsigned short* wzthi = (unsigned short*)(ws + 67174400 + 1048576);
    unsigned short* wztlo = (unsigned short*)(ws + 67174400 + 1572864);
    float* partials      = (float*)(ws + 33619968);

    const bool fast = ws_size >= 637861888ull;

    hipMemsetAsync(table, 0, (size_t)NQ * 8, stream);

    k_split<<<1024, 256, 0, stream>>>(emb, embhi, emblo, NEMB * DD / 4);
    k_split<<<256, 256, 0, stream>>>(Wp, wphi, wplo, DD * DD / 4);
    k_wtsplit<<<dim3(16, 16), 256, 0, stream>>>(Wz, wzthi, wztlo);

    k_qc_mfma<<<dim3(DD / 128, NEMB / 128), 256, 0, stream>>>(embhi, emblo, wphi, wplo,
                                                              bp, qc, qchi, qclo);
    k_norm<<<NEMB, 256, 0, stream>>>(qc, bz, rnorm, tvec);
    k_e_mfma<<<dim3(DD / 128, NEMB / 128), 256, 0, stream>>>(qchi, qclo, wzthi, wztlo,
                                                             rnorm, ehi, elo);
    if (fast) {
        k_split_hi<<<4096, 256, 0, stream>>>(z, zhi, NQ * DD / 4);
        k_scores1<<<dim3(NEMB / 128, NQ / 128), 256, 0, stream>>>(zhi, ehi, tvec, table, scores);
        k_select<<<NQ, 256, 0, stream>>>(table, scores, z, tvec, ehi, elo, qc,
                                         out, partials, out + (size_t)NQ * DD + 1);
    } else {
        k_split<<<4096, 256, 0, stream>>>(z, zhi, zlo, NQ * DD / 4);
        k_scores<<<dim3(NEMB / 128, NQ / 128), 256, 0, stream>>>(zhi, zlo, ehi, elo, tvec, table);
        k_gather<<<NQ, 128, 0, stream>>>(table, qc, z, out, partials,
                                         out + (size_t)NQ * DD + 1);
    }
    k_loss<<<1, 1024, 0, stream>>>(partials, out + (size_t)NQ * DD);
}